// Round 4
// baseline (400.949 us; speedup 1.0000x reference)
//
#include <hip/hip_runtime.h>
#include <math.h>

#define NROWS 16      // B*QL
#define NCOLS 6144    // q 4096 | k 1024 | v 1024
#define HID   4096
#define NKV   8
#define HD    128
#define PRIOR 4096
#define NCH   32      // KV chunks in attention kernel
#define CHUNK 128     // keys per chunk
#define SUB   64      // keys per subtile
#define KC1   128     // K-chunk for projection kernels
#define NKC   32      // 4096 / KC1

// ---------------------------------------------------------------------------
// K1: fused QKV projection, split-K partials.  part[NKC][16][6144]
// grid (24, 32) x 256.  Wave w owns rows w*4..+3 (acc = 16 VGPR); lane owns
// 4 cols (float4 weight loads, 16B/lane).  All 4 waves read the same weight
// tile -> L1/L2 reuse; HBM sees each weight once.  128 independent b128
// loads per thread = deep VMEM pipeline.
// ---------------------------------------------------------------------------
__global__ __launch_bounds__(256, 4)
void k_qkv_partial(const float* __restrict__ hid,
                   const float* __restrict__ wq,
                   const float* __restrict__ wk,
                   const float* __restrict__ wv,
                   float* __restrict__ part)
{
    const int t = threadIdx.x, lane = t & 63, w = t >> 6;
    const int tile = blockIdx.x, kc = blockIdx.y, k0 = kc * KC1;
    __shared__ float sA[NROWS][KC1];           // 8 KB activation chunk
    for (int i = t; i < 512; i += 256) {
        const int r = i >> 5, kk = (i & 31) * 4;
        *(float4*)(&sA[r][kk]) = *(const float4*)(hid + (size_t)r * HID + k0 + kk);
    }
    const int col = tile * 256 + lane * 4;     // 256-col tiles: choice block-uniform
    const float* wsel; int wn, wcol;
    if (tile < 16)      { wsel = wq; wn = 4096; wcol = col; }
    else if (tile < 20) { wsel = wk; wn = 1024; wcol = col - 4096; }
    else                { wsel = wv; wn = 1024; wcol = col - 5120; }
    const float* wp = wsel + (size_t)k0 * wn + wcol;
    __syncthreads();

    float acc[4][4];
#pragma unroll
    for (int i = 0; i < 4; i++)
#pragma unroll
        for (int j = 0; j < 4; j++) acc[i][j] = 0.f;

#pragma unroll 4
    for (int kk = 0; kk < KC1; kk += 4) {
        const float4 w0 = *(const float4*)(wp + (size_t)(kk + 0) * wn);
        const float4 w1 = *(const float4*)(wp + (size_t)(kk + 1) * wn);
        const float4 w2 = *(const float4*)(wp + (size_t)(kk + 2) * wn);
        const float4 w3 = *(const float4*)(wp + (size_t)(kk + 3) * wn);
#pragma unroll
        for (int i = 0; i < 4; i++) {
            const float4 a = *(const float4*)(&sA[w * 4 + i][kk]);   // broadcast b128
            acc[i][0] = fmaf(a.x, w0.x, fmaf(a.y, w1.x, fmaf(a.z, w2.x, fmaf(a.w, w3.x, acc[i][0]))));
            acc[i][1] = fmaf(a.x, w0.y, fmaf(a.y, w1.y, fmaf(a.z, w2.y, fmaf(a.w, w3.y, acc[i][1]))));
            acc[i][2] = fmaf(a.x, w0.z, fmaf(a.y, w1.z, fmaf(a.z, w2.z, fmaf(a.w, w3.z, acc[i][2]))));
            acc[i][3] = fmaf(a.x, w0.w, fmaf(a.y, w1.w, fmaf(a.z, w2.w, fmaf(a.w, w3.w, acc[i][3]))));
        }
    }
    float* po = part + (size_t)kc * (NROWS * NCOLS) + col;
#pragma unroll
    for (int i = 0; i < 4; i++)
        *(float4*)(po + (size_t)(w * 4 + i) * NCOLS) =
            make_float4(acc[i][0], acc[i][1], acc[i][2], acc[i][3]);
}

// ---------------------------------------------------------------------------
// K2: reduce split-K partials + RoPE (q scaled by 1/sqrt(HD)).
// ---------------------------------------------------------------------------
__global__ __launch_bounds__(256)
void k_reduce_rope(const float* __restrict__ part, float* __restrict__ qkv)
{
    const int tid = blockIdx.x * 256 + threadIdx.x;
    const double L64 = 0.21586735246819178;   // ln(1e6)/64

    if (tid < 32768) {                         // ---- q pairs ----
        const int d = tid & 63, h = (tid >> 6) & 31, r = tid >> 11;
        const int c1 = h * HD + d;
        float s1 = 0.f, s2 = 0.f;
        for (int c = 0; c < NKC; c++) {
            const float* p = part + (size_t)c * (NROWS * NCOLS) + r * NCOLS + c1;
            s1 += p[0]; s2 += p[64];
        }
        const double ang = (double)(PRIOR + (r & 3)) * exp(-(double)d * L64);
        double sv, cv; sincos(ang, &sv, &cv);
        const float cf = (float)cv, sf = (float)sv, sc = 0.08838834764831845f;
        qkv[r * NCOLS + c1]      = (s1 * cf - s2 * sf) * sc;
        qkv[r * NCOLS + c1 + 64] = (s2 * cf + s1 * sf) * sc;
    } else if (tid < 40960) {                  // ---- k_active pairs ----
        const int idx = tid - 32768;
        const int d = idx & 63, kh = (idx >> 6) & 7, r = idx >> 9;
        const int c1 = 4096 + kh * HD + d;
        float s1 = 0.f, s2 = 0.f;
        for (int c = 0; c < NKC; c++) {
            const float* p = part + (size_t)c * (NROWS * NCOLS) + r * NCOLS + c1;
            s1 += p[0]; s2 += p[64];
        }
        const double ang = (double)(PRIOR + (r & 3)) * exp(-(double)d * L64);
        double sv, cv; sincos(ang, &sv, &cv);
        const float cf = (float)cv, sf = (float)sv;
        qkv[r * NCOLS + c1]      = s1 * cf - s2 * sf;
        qkv[r * NCOLS + c1 + 64] = s2 * cf + s1 * sf;
    } else {                                   // ---- v_active ----
        const int idx = tid - 40960;
        const int n = idx & 1023, r = idx >> 10;
        const int c1 = 5120 + n;
        float s = 0.f;
        for (int c = 0; c < NKC; c++)
            s += part[(size_t)c * (NROWS * NCOLS) + r * NCOLS + c1];
        qkv[r * NCOLS + c1] = s;
    }
}

// ---------------------------------------------------------------------------
// K3: flash-decoding over prior KV.  grid (32, 8, 4) = 1024 blocks = 4/CU.
// No K-LDS: lane=key streams its own K row from global (32 independent b128
// loads); Q broadcast from LDS.  Wave-private online softmax.  PV: 64
// independent b128 V loads/thread, probs via pP[64][20] LDS (conflict-free).
// LDS ~13.7 KB, 2 barriers/subtile.
// ---------------------------------------------------------------------------
__global__ __launch_bounds__(256, 4)
void k_attn_prior(const float* __restrict__ qkv,
                  const float* __restrict__ pk,
                  const float* __restrict__ pv,
                  float* __restrict__ part3)
{
    const int chunk = blockIdx.x, kvh = blockIdx.y, b = blockIdx.z;
    const int t = threadIdx.x, lane = t & 63;

    __shared__ float qR[NROWS][132];   // rows x d (pad 132: 528B rows, 16B-aligned)
    __shared__ float pP[SUB][20];      // probs [key][row] (stride-20: b128 conflict-free)
    __shared__ float aS[NROWS];        // per-row alpha

    const int qt = t >> 6;             // wave id -> rows qt*4..+3
    const int d4 = t & 31;             // PV: d = d4*4..+3
    const int rp = t >> 5;             // PV: rows rp*2, rp*2+1

    const size_t kvoff = ((size_t)(b * NKV + kvh) * PRIOR + (size_t)chunk * CHUNK) * HD;
    const float* kbase = pk + kvoff;
    const float* vbase = pv + kvoff;

    // stage Q rows (r = g*4+ql), coalesced
    for (int i = t; i < 2048; i += 256) {
        const int d = i & 127, r = i >> 4 >> 3;   // r = i>>7
        const int ql = r & 3, g = r >> 2;
        qR[r][d] = qkv[(size_t)(b * 4 + ql) * NCOLS + (kvh * 4 + g) * HD + d];
    }

    float m_r[4], l_r[4];
#pragma unroll
    for (int i = 0; i < 4; i++) { m_r[i] = -INFINITY; l_r[i] = 0.f; }
    float o[2][4] = {{0.f,0.f,0.f,0.f},{0.f,0.f,0.f,0.f}};
    __syncthreads();

    for (int st = 0; st < CHUNK / SUB; st++) {
        // ---- scores: lane = key, 32 independent global b128 K loads ----
        const float* kr = kbase + (size_t)(st * SUB + lane) * HD;
        const float* q0 = &qR[qt * 4 + 0][0];
        const float* q1 = &qR[qt * 4 + 1][0];
        const float* q2 = &qR[qt * 4 + 2][0];
        const float* q3 = &qR[qt * 4 + 3][0];
        float s0 = 0.f, s1 = 0.f, s2 = 0.f, s3 = 0.f;
#pragma unroll 8
        for (int d = 0; d < HD; d += 4) {
            const float4 k4 = *(const float4*)(kr + d);
            const float4 qa = *(const float4*)(q0 + d);
            const float4 qb = *(const float4*)(q1 + d);
            const float4 qc = *(const float4*)(q2 + d);
            const float4 qd = *(const float4*)(q3 + d);
            s0 = fmaf(qa.x,k4.x, fmaf(qa.y,k4.y, fmaf(qa.z,k4.z, fmaf(qa.w,k4.w, s0))));
            s1 = fmaf(qb.x,k4.x, fmaf(qb.y,k4.y, fmaf(qb.z,k4.z, fmaf(qb.w,k4.w, s1))));
            s2 = fmaf(qc.x,k4.x, fmaf(qc.y,k4.y, fmaf(qc.z,k4.z, fmaf(qc.w,k4.w, s2))));
            s3 = fmaf(qd.x,k4.x, fmaf(qd.y,k4.y, fmaf(qd.z,k4.z, fmaf(qd.w,k4.w, s3))));
        }
        // ---- wave-private online softmax (rows qt*4..+3, lanes = 64 keys) ----
        float sv[4] = {s0, s1, s2, s3};
        float mx[4] = {s0, s1, s2, s3};
        for (int off = 32; off; off >>= 1) {
#pragma unroll
            for (int i = 0; i < 4; i++) mx[i] = fmaxf(mx[i], __shfl_xor(mx[i], off));
        }
        float pr[4], sm[4], al[4];
#pragma unroll
        for (int i = 0; i < 4; i++) {
            const float mn = fmaxf(m_r[i], mx[i]);
            pr[i] = __expf(sv[i] - mn);
            al[i] = __expf(m_r[i] - mn);     // first subtile: exp(-inf)=0
            m_r[i] = mn;
            sm[i] = pr[i];
        }
        *(float4*)(&pP[lane][qt * 4]) = make_float4(pr[0], pr[1], pr[2], pr[3]);
        for (int off = 32; off; off >>= 1) {
#pragma unroll
            for (int i = 0; i < 4; i++) sm[i] += __shfl_xor(sm[i], off);
        }
#pragma unroll
        for (int i = 0; i < 4; i++) l_r[i] = l_r[i] * al[i] + sm[i];
        if (lane == 0) {
#pragma unroll
            for (int i = 0; i < 4; i++) aS[qt * 4 + i] = al[i];
        }
        __syncthreads();   // pP/aS visible

        // ---- PV: 64 independent global b128 V loads; p broadcast from LDS ----
        {
            const float a0 = aS[rp * 2], a1 = aS[rp * 2 + 1];
#pragma unroll
            for (int j = 0; j < 4; j++) { o[0][j] *= a0; o[1][j] *= a1; }
            const float* vs = vbase + (size_t)st * SUB * HD + d4 * 4;
#pragma unroll 8
            for (int key = 0; key < SUB; key++) {
                const float4 v4 = *(const float4*)(vs + (size_t)key * HD);
                const float p0 = pP[key][rp * 2];
                const float p1 = pP[key][rp * 2 + 1];
                o[0][0]=fmaf(p0,v4.x,o[0][0]); o[0][1]=fmaf(p0,v4.y,o[0][1]);
                o[0][2]=fmaf(p0,v4.z,o[0][2]); o[0][3]=fmaf(p0,v4.w,o[0][3]);
                o[1][0]=fmaf(p1,v4.x,o[1][0]); o[1][1]=fmaf(p1,v4.y,o[1][1]);
                o[1][2]=fmaf(p1,v4.z,o[1][2]); o[1][3]=fmaf(p1,v4.w,o[1][3]);
            }
        }
        __syncthreads();   // pP reads done before next subtile's writes
    }

    // ---- write chunk partial: m[16], l[16], o[16][128] ----
    float* pout = part3 + (size_t)((b * NKV + kvh) * NCH + chunk) * 2080;
    if (lane == 0) {
#pragma unroll
        for (int i = 0; i < 4; i++) { pout[qt * 4 + i] = m_r[i]; pout[16 + qt * 4 + i] = l_r[i]; }
    }
#pragma unroll
    for (int j = 0; j < 2; j++)
        *(float4*)(pout + 32 + (size_t)(rp * 2 + j) * HD + d4 * 4) =
            make_float4(o[j][0], o[j][1], o[j][2], o[j][3]);
}

// ---------------------------------------------------------------------------
// K4: combine chunk partials + causal active keys (shared max / divisor).
// grid (8,8,4)=256 blocks: x = g + 4*dh (d-half split), y = kvh, z = b.
// ---------------------------------------------------------------------------
__global__ __launch_bounds__(256)
void k_combine(const float* __restrict__ qkv,
               const float* __restrict__ part3,
               float* __restrict__ attn)
{
    const int g = blockIdx.x & 3, dh = blockIdx.x >> 2;
    const int kvh = blockIdx.y, b = blockIdx.z;
    const int t = threadIdx.x;
    __shared__ float qL[4][128], kA[4][128], vA[4][64];
    __shared__ float mC[NCH][4], lC[NCH][4], fC[NCH][4];
    __shared__ float sAct[4][4], pA[4][4], invL[4];

    for (int i = t; i < 512; i += 256) {
        const int ql = i >> 7, d = i & 127;
        qL[ql][d] = qkv[(size_t)(b * 4 + ql) * NCOLS + (kvh * 4 + g) * HD + d];
        kA[ql][d] = qkv[(size_t)(b * 4 + ql) * NCOLS + 4096 + kvh * HD + d];
    }
    {
        const int ql = t >> 6, d = t & 63;
        vA[ql][d] = qkv[(size_t)(b * 4 + ql) * NCOLS + 5120 + kvh * HD + dh * 64 + d];
    }
    const float* p3 = part3 + (size_t)(b * NKV + kvh) * NCH * 2080;
    for (int i = t; i < NCH * 4; i += 256) {
        const int c = i >> 2, lr = i & 3;
        mC[c][lr] = p3[c * 2080 + g * 4 + lr];
        lC[c][lr] = p3[c * 2080 + 16 + g * 4 + lr];
    }
    __syncthreads();
    if (t < 16) {                        // active scores (q pre-scaled by 1/sqrt(HD))
        const int lr = t >> 2, k = t & 3;
        float s = 0.f;
        for (int d = 0; d < HD; d++) s = fmaf(qL[lr][d], kA[k][d], s);
        sAct[lr][k] = s;
    }
    __syncthreads();
    if (t < 4) {                         // per-row global stats (lr == ql)
        const int lr = t;
        float M = -INFINITY;
        for (int c = 0; c < NCH; c++) M = fmaxf(M, mC[c][lr]);
        for (int k = 0; k <= lr; k++) M = fmaxf(M, sAct[lr][k]);
        float l = 0.f;
        for (int c = 0; c < NCH; c++) {
            const float f = __expf(mC[c][lr] - M);
            fC[c][lr] = f;
            l = fmaf(f, lC[c][lr], l);
        }
#pragma unroll
        for (int k = 0; k < 4; k++) {
            const float p = (k <= lr) ? __expf(sAct[lr][k] - M) : 0.f;
            pA[lr][k] = p; l += p;
        }
        invL[lr] = 1.f / l;
    }
    __syncthreads();

    const int d2 = t & 63, lr = t >> 6;
    const float* pb = p3 + 32 + (size_t)(g * 4 + lr) * HD + dh * 64 + d2;
    float o = 0.f;
    for (int c = 0; c < NCH; c++)
        o = fmaf(fC[c][lr], pb[(size_t)c * 2080], o);
#pragma unroll
    for (int k = 0; k < 4; k++)
        o = fmaf(pA[lr][k], vA[k][d2], o);
    attn[(size_t)(b * 4 + lr) * HID + (kvh * 4 + g) * HD + dh * 64 + d2] = o * invL[lr];
}

// ---------------------------------------------------------------------------
// K5: output projection split-K partials.  part[NKC][16][4096], grid (16,32).
// Same wave-row-split structure as K1.
// ---------------------------------------------------------------------------
__global__ __launch_bounds__(256, 4)
void k_out_partial(const float* __restrict__ attn,
                   const float* __restrict__ wo,
                   float* __restrict__ part)
{
    const int t = threadIdx.x, lane = t & 63, w = t >> 6;
    const int tile = blockIdx.x, kc = blockIdx.y, k0 = kc * KC1;
    __shared__ float sA[NROWS][KC1];
    for (int i = t; i < 512; i += 256) {
        const int r = i >> 5, kk = (i & 31) * 4;
        *(float4*)(&sA[r][kk]) = *(const float4*)(attn + (size_t)r * HID + k0 + kk);
    }
    const int col = tile * 256 + lane * 4;
    const float* wp = wo + (size_t)k0 * HID + col;
    __syncthreads();

    float acc[4][4];
#pragma unroll
    for (int i = 0; i < 4; i++)
#pragma unroll
        for (int j = 0; j < 4; j++) acc[i][j] = 0.f;

#pragma unroll 4
    for (int kk = 0; kk < KC1; kk += 4) {
        const float4 w0 = *(const float4*)(wp + (size_t)(kk + 0) * HID);
        const float4 w1 = *(const float4*)(wp + (size_t)(kk + 1) * HID);
        const float4 w2 = *(const float4*)(wp + (size_t)(kk + 2) * HID);
        const float4 w3 = *(const float4*)(wp + (size_t)(kk + 3) * HID);
#pragma unroll
        for (int i = 0; i < 4; i++) {
            const float4 a = *(const float4*)(&sA[w * 4 + i][kk]);
            acc[i][0] = fmaf(a.x, w0.x, fmaf(a.y, w1.x, fmaf(a.z, w2.x, fmaf(a.w, w3.x, acc[i][0]))));
            acc[i][1] = fmaf(a.x, w0.y, fmaf(a.y, w1.y, fmaf(a.z, w2.y, fmaf(a.w, w3.y, acc[i][1]))));
            acc[i][2] = fmaf(a.x, w0.z, fmaf(a.y, w1.z, fmaf(a.z, w2.z, fmaf(a.w, w3.z, acc[i][2]))));
            acc[i][3] = fmaf(a.x, w0.w, fmaf(a.y, w1.w, fmaf(a.z, w2.w, fmaf(a.w, w3.w, acc[i][3]))));
        }
    }
    float* po = part + (size_t)kc * (NROWS * HID) + col;
#pragma unroll
    for (int i = 0; i < 4; i++)
        *(float4*)(po + (size_t)(w * 4 + i) * HID) =
            make_float4(acc[i][0], acc[i][1], acc[i][2], acc[i][3]);
}

// K5b: reduce out-proj partials -> d_out.  256 blocks, coalesced scalar.
__global__ __launch_bounds__(256)
void k_out_reduce(const float* __restrict__ part, float* __restrict__ out)
{
    const int tid = blockIdx.x * 256 + threadIdx.x;   // 65536
    float s = 0.f;
    for (int c = 0; c < NKC; c++) s += part[(size_t)c * (NROWS * HID) + tid];
    out[tid] = s;
}

// ---------------------------------------------------------------------------
extern "C" void kernel_launch(void* const* d_in, const int* in_sizes, int n_in,
                              void* d_out, int out_size, void* d_ws, size_t ws_size,
                              hipStream_t stream)
{
    (void)in_sizes; (void)n_in; (void)out_size; (void)ws_size;
    const float* hid = (const float*)d_in[0];
    const float* pk  = (const float*)d_in[1];
    const float* pv  = (const float*)d_in[2];
    const float* wq  = (const float*)d_in[3];
    const float* wk  = (const float*)d_in[4];
    const float* wv  = (const float*)d_in[5];
    const float* wo  = (const float*)d_in[6];
    float* out = (float*)d_out;
    float* ws  = (float*)d_ws;

    // workspace (floats); sequential lifetimes share region 0:
    //   P1 [k1->k2] 3,145,728 | P3 [k3->k4] 2,129,920 | P5 [k5->k5b] 2,097,152
    float* P1   = ws;
    float* P3   = ws;
    float* P5   = ws;
    float* qkv  = ws + 3145728;            // 98,304
    float* attn = ws + 3244032;            // 65,536   (total 13.24 MB)

    k_qkv_partial<<<dim3(24, NKC), 256, 0, stream>>>(hid, wq, wk, wv, P1);
    k_reduce_rope<<<224, 256, 0, stream>>>(P1, qkv);
    k_attn_prior<<<dim3(NCH, NKV, 4), 256, 0, stream>>>(qkv, pk, pv, P3);
    k_combine<<<dim3(8, 8, 4), 256, 0, stream>>>(qkv, P3, attn);
    k_out_partial<<<dim3(16, NKC), 256, 0, stream>>>(attn, wo, P5);
    k_out_reduce<<<256, 256, 0, stream>>>(P5, out);
}